// Round 4
// baseline (487.120 us; speedup 1.0000x reference)
//
#include <hip/hip_runtime.h>
#include <hip/hip_bf16.h>

// bf16 implicit-GEMM 3x3 conv for x:(16,64,224,224) f32, W:(64,64,3,3) f32, b:(64).
// 9 tap-shifted GEMMs (M=pixels, N=64 kout, K=64 c) on v_mfma_f32_32x32x16_bf16.
// Round-4: concurrency round. Evidence: removing 190MB traffic (r2) DROPPED BW
// 2.77->2.05 TB/s at ~equal dur => MLP-limited, not byte-limited (Little: ~3KB/CU
// in flight). r1 proved 512thr/acc[2][2] doubles resident waves and sustains
// 2.74 TB/s (its regression was its store pattern, reverted here). Changes:
//  (a) 512 thr / 8 waves, wave owns 2 rows, acc[2][2]=64 regs -> 16 waves/CU.
//  (b) staging in batches of 3 items: issue all 24 scalar loads, THEN convert+
//      write (vmcnt is FIFO -> per-item load->wait->write serialized; batching
//      triples outstanding loads/wave). Lane-consecutive 16B LDS writes (the
//      round-2 conflict-free pattern; round-3's 64B-stride writes -> 2.5M confl).
// Kept: XCD-chunked swizzle (196 tiles = 2 images/XCD), 16x32x64 tile, LDS
// [h][cg][w][c8] 78336B -> 2 blocks/CU, round-0 float4 epilogue (proven bytes).

typedef __attribute__((ext_vector_type(8)))  short   short8;
typedef __attribute__((ext_vector_type(8)))  unsigned short ushort8;
typedef __attribute__((ext_vector_type(16))) float   float16_t;

#define HW (224 * 224)

__device__ __forceinline__ unsigned short f2bf(float f) {
  __hip_bfloat16 h = __float2bfloat16(f);  // RNE
  return *reinterpret_cast<unsigned short*>(&h);
}

// ---- pre-kernel: Wt[tap][kout][c] bf16 <- W[kout][c][tap] fp32 ----
__global__ void build_wt(const float* __restrict__ W, unsigned short* __restrict__ wt) {
  int i = blockIdx.x * 256 + threadIdx.x;  // 0 .. 36863
  if (i < 9 * 64 * 64) {
    int tap = i >> 12;          // /4096
    int rem = i & 4095;
    int nn  = rem >> 6;
    int c   = rem & 63;
    wt[i] = f2bf(W[(nn * 64 + c) * 9 + tap]);
  }
}

// ---- main kernel ----
// Grid: 1568 1-D blocks = 7 w-tiles x 14 h-tiles x 16 images, XCD-swizzled.
__global__ __launch_bounds__(512, 4) void conv3x3_mfma(
    const float* __restrict__ x, const unsigned short* __restrict__ wt,
    const float* __restrict__ bias, float* __restrict__ out) {
  __shared__ __align__(16) unsigned short xs[18 * 8 * 34 * 8];  // [h][cg][w][c8]

  // XCD-chunked swizzle: hw assigns XCD = bid % 8 (round-robin, m09).
  // Map each XCD's blocks to a CONTIGUOUS 196-tile chunk (= 2 whole images)
  // so halo/edge cache lines are shared within one L2. 1568 % 8 == 0.
  const int bid = blockIdx.x;
  const int t   = (bid & 7) * 196 + (bid >> 3);
  const int bx  = t % 7;
  const int rem_t = t / 7;
  const int by  = rem_t % 14;
  const int img = rem_t / 14;

  const int w0  = bx * 32;
  const int h0  = by * 16;
  const int tid = threadIdx.x;
  const int lane = tid & 63, wave = tid >> 6;
  const int ln31 = lane & 31, lhi = lane >> 5;

  const float* xn = x + (size_t)img * 64 * HW;

  // ---- stage 18x34 halo tile, scalar loads in batches of 3 items ----
  // Item i = (h, cg, w): 8 scalar f32 loads (channel-strided), pack ushort8.
  // Adjacent lanes -> adjacent w: coalesced 4B global reads, conflict-free
  // lane-consecutive 16B LDS writes. Batch: issue 24 loads, then convert+write.
  const int NITEMS = 18 * 8 * 34;  // 4896; /512 = 9.5625 items/thread
  for (int base = tid; base < NITEMS; base += 512 * 3) {
    float va[3][8];
    int   iw[3];
#pragma unroll
    for (int it = 0; it < 3; ++it) {
      const int i = base + it * 512;
      iw[it] = i;
      if (i < NITEMS) {
        const int h   = i / (8 * 34);
        const int rem = i - h * (8 * 34);
        const int cg  = rem / 34;
        const int w   = rem - cg * 34;
        const int gh  = h0 - 1 + h;
        const int gw  = w0 - 1 + w;
        if (((unsigned)gh < 224u) && ((unsigned)gw < 224u)) {
          const float* p = xn + (size_t)cg * 8 * HW + gh * 224 + gw;
#pragma unroll
          for (int j = 0; j < 8; ++j) va[it][j] = p[(size_t)j * HW];
        } else {
#pragma unroll
          for (int j = 0; j < 8; ++j) va[it][j] = 0.f;
        }
      }
    }
#pragma unroll
    for (int it = 0; it < 3; ++it) {
      if (iw[it] < NITEMS) {
        ushort8 pk;
#pragma unroll
        for (int j = 0; j < 8; ++j) pk[j] = f2bf(va[it][j]);
        *reinterpret_cast<ushort8*>(&xs[iw[it] * 8]) = pk;
      }
    }
  }
  __syncthreads();

  // ---- MFMA main loop: 9 taps x 4 ksteps x 2 row-blocks x 2 n-blocks ----
  // Wave owns rows {2*wave, 2*wave+1} x 32 cols x all 64 kout.
  const int row0 = wave * 2;
  float16_t acc[2][2];
#pragma unroll
  for (int rb = 0; rb < 2; ++rb)
#pragma unroll
    for (int nb = 0; nb < 2; ++nb) acc[rb][nb] = 0.f;

#pragma unroll
  for (int r = 0; r < 3; ++r) {
#pragma unroll
    for (int s = 0; s < 3; ++s) {
      const int tap = r * 3 + s;
      // B-frags for this tap: B[k=c][n=kout], lane: n=ln31, k=lhi*8+j
      short8 bq[4][2];
#pragma unroll
      for (int ks = 0; ks < 4; ++ks)
#pragma unroll
        for (int nb = 0; nb < 2; ++nb)
          bq[ks][nb] = *reinterpret_cast<const short8*>(
              wt + ((tap * 64 + nb * 32 + ln31) * 64 + ks * 16 + lhi * 8));

#pragma unroll
      for (int ks = 0; ks < 4; ++ks) {
        const int cg = ks * 2 + lhi;
#pragma unroll
        for (int rb = 0; rb < 2; ++rb) {
          const int hidx = row0 + rb + r;
          const int widx = ln31 + s;
          const short8 a = *reinterpret_cast<const short8*>(
              &xs[(((hidx * 8) + cg) * 34 + widx) * 8]);
          acc[rb][0] = __builtin_amdgcn_mfma_f32_32x32x16_bf16(a, bq[ks][0], acc[rb][0], 0, 0, 0);
          acc[rb][1] = __builtin_amdgcn_mfma_f32_32x32x16_bf16(a, bq[ks][1], acc[rb][1], 0, 0, 0);
        }
      }
    }
  }

  // ---- epilogue: D lane mapping m=(reg&3)+8*(reg>>2)+4*lhi, n=ln31 ----
  // (round-0 pattern: ch = nb*32+ln31, float4 along w; proven 284MB WRITE_SIZE)
#pragma unroll
  for (int rb = 0; rb < 2; ++rb) {
    const int h = h0 + row0 + rb;
#pragma unroll
    for (int nb = 0; nb < 2; ++nb) {
      const int ch = nb * 32 + ln31;
      const float bv = bias[ch];
      float* op = out + (((size_t)img * 64 + ch) * 224 + h) * 224 + w0;
#pragma unroll
      for (int q = 0; q < 4; ++q) {
        const int wloc = 8 * q + 4 * lhi;
        float4 v;
        v.x = acc[rb][nb][4 * q + 0] + bv;
        v.y = acc[rb][nb][4 * q + 1] + bv;
        v.z = acc[rb][nb][4 * q + 2] + bv;
        v.w = acc[rb][nb][4 * q + 3] + bv;
        *reinterpret_cast<float4*>(op + wloc) = v;
      }
    }
  }
}

// ---- fallback (round-1 direct fp32) if d_ws is too small for Wt ----
#define TW 32
#define TH 32
#define KB 16
#define PXT 4
__global__ __launch_bounds__(256) void conv3x3_direct(
    const float* __restrict__ x, const float* __restrict__ wgt,
    const float* __restrict__ bias, float* __restrict__ out) {
  __shared__ float xsf[34 * 35];
  const int tx = blockIdx.x % 7, ty = blockIdx.x / 7;
  const int k0 = blockIdx.y * KB, n = blockIdx.z;
  const int w0 = tx * TW, h0 = ty * TH;
  const int tid = threadIdx.x;
  const int tw = tid & 7, th = tid >> 3;
  float acc[KB][PXT];
#pragma unroll
  for (int k = 0; k < KB; ++k)
#pragma unroll
    for (int p = 0; p < PXT; ++p) acc[k][p] = 0.f;
  const float* xn = x + (size_t)n * 64 * HW;
  for (int c = 0; c < 64; ++c) {
    const float* xc = xn + (size_t)c * HW;
    for (int i = tid; i < 34 * 34; i += 256) {
      int row = i / 34, col = i - row * 34;
      int gh = h0 - 1 + row, gw = w0 - 1 + col;
      float v = 0.f;
      if (gh >= 0 && gh < 224 && gw >= 0 && gw < 224) v = xc[gh * 224 + gw];
      xsf[row * 35 + col] = v;
    }
    __syncthreads();
    float in[3][6];
#pragma unroll
    for (int r = 0; r < 3; ++r)
#pragma unroll
      for (int q = 0; q < 6; ++q) in[r][q] = xsf[(th + r) * 35 + tw * PXT + q];
    const float* wc = wgt + ((size_t)k0 * 64 + c) * 9;
#pragma unroll
    for (int k = 0; k < KB; ++k) {
      const float* wk = wc + (size_t)k * 64 * 9;
#pragma unroll
      for (int r = 0; r < 3; ++r)
#pragma unroll
        for (int s = 0; s < 3; ++s) {
          float wv = wk[r * 3 + s];
#pragma unroll
          for (int p = 0; p < PXT; ++p) acc[k][p] += wv * in[r][s + p];
        }
    }
    __syncthreads();
  }
#pragma unroll
  for (int k = 0; k < KB; ++k) {
    float bv = bias[k0 + k];
    float4 v = make_float4(acc[k][0] + bv, acc[k][1] + bv, acc[k][2] + bv, acc[k][3] + bv);
    float* op = out + ((((size_t)n * 64 + (k0 + k)) * 224 + (h0 + th)) * 224 + (w0 + tw * PXT));
    *reinterpret_cast<float4*>(op) = v;
  }
}

extern "C" void kernel_launch(void* const* d_in, const int* in_sizes, int n_in,
                              void* d_out, int out_size, void* d_ws, size_t ws_size,
                              hipStream_t stream) {
  const float* x = (const float*)d_in[0];
  const float* W = (const float*)d_in[1];
  const float* b = (const float*)d_in[2];
  float* out = (float*)d_out;

  if (ws_size >= 9 * 64 * 64 * sizeof(unsigned short)) {
    unsigned short* wt = (unsigned short*)d_ws;
    build_wt<<<144, 256, 0, stream>>>(W, wt);
    conv3x3_mfma<<<1568, 512, 0, stream>>>(x, wt, b, out);  // 7x14x16 tiles, XCD-swizzled
  } else {
    dim3 grid(7 * 7, 64 / KB, 16);
    conv3x3_direct<<<grid, 256, 0, stream>>>(x, W, b, out);
  }
}

// Round 6
// 483.558 us; speedup vs baseline: 1.0074x; 1.0074x over previous
//
#include <hip/hip_runtime.h>
#include <hip/hip_bf16.h>

// bf16 implicit-GEMM 3x3 conv for x:(16,64,224,224) f32, W:(64,64,3,3) f32, b:(64).
// 9 tap-shifted GEMMs (M=pixels, N=64 kout, K=64 c) on v_mfma_f32_32x32x16_bf16.
// Round-6: RESUBMIT of round-5 (container acquire failed twice -> no data; kernel
// re-audited: no OOB, no divergent barriers, no capture violations).
// QUARTER-PIPELINED STAGING (T14-style). Evidence r0-r4: dur ~220us invariant vs
// bytes (655->390MB) and vs occupancy (19->38%) => per-CU line-request rate
// limited (~100 lines/us/CU), requests BURSTED in a monolithic stage phase then
// memory idle during MFMA. Change: split K=64c into 4 quarters of 16c (one MFMA
// K-step each), two quarter LDS buffers (39KB total):
//   stage Q0 -> barrier -> for q=0..3 { issue Q(q+1) global loads into regs;
//   MFMA quarter q from buf[q&1]; vmcnt+convert+write buf[(q+1)&1]; barrier }
// Load latency of Q1..Q3 hides under MFMA; request stream is smoothed.
// Config: 512 thr / 8 waves, wave owns 2 rows, acc[2][2]=64; pf=24 VGPR ->
// ~160 unified regs -> 1 block/CU (intra-block pipeline replaces 2-block overlap).
// Kept: XCD-chunked swizzle, conflict-free lane-consecutive staging, r4 epilogue
// (241MB WRITE, best measured), wt[tap][kout][c] in d_ws.

typedef __attribute__((ext_vector_type(8)))  short   short8;
typedef __attribute__((ext_vector_type(8)))  unsigned short ushort8;
typedef __attribute__((ext_vector_type(16))) float   float16_t;

#define HW (224 * 224)

__device__ __forceinline__ unsigned short f2bf(float f) {
  __hip_bfloat16 h = __float2bfloat16(f);  // RNE
  return *reinterpret_cast<unsigned short*>(&h);
}

// ---- pre-kernel: Wt[tap][kout][c] bf16 <- W[kout][c][tap] fp32 ----
__global__ void build_wt(const float* __restrict__ W, unsigned short* __restrict__ wt) {
  int i = blockIdx.x * 256 + threadIdx.x;  // 0 .. 36863
  if (i < 9 * 64 * 64) {
    int tap = i >> 12;          // /4096
    int rem = i & 4095;
    int nn  = rem >> 6;
    int c   = rem & 63;
    wt[i] = f2bf(W[(nn * 64 + c) * 9 + tap]);
  }
}

// ---- main kernel ----
// Grid: 1568 1-D blocks = 7 w-tiles x 14 h-tiles x 16 images, XCD-swizzled.
__global__ __launch_bounds__(512, 2) void conv3x3_mfma(
    const float* __restrict__ x, const unsigned short* __restrict__ wt,
    const float* __restrict__ bias, float* __restrict__ out) {
  // Two quarter-buffers: [buf][h(18)][cgl(2)][w(34)][c8(8)] bf16 = 2*19584 shorts.
  __shared__ __align__(16) unsigned short xs[2][18 * 2 * 34 * 8];

  // XCD-chunked swizzle: hw assigns XCD = bid % 8. Contiguous 196-tile chunk
  // (= 2 whole images) per XCD so halo/edge lines are L2-shared. 1568 % 8 == 0.
  const int bid = blockIdx.x;
  const int t   = (bid & 7) * 196 + (bid >> 3);
  const int bx  = t % 7;
  const int rem_t = t / 7;
  const int by  = rem_t % 14;
  const int img = rem_t / 14;

  const int w0  = bx * 32;
  const int h0  = by * 16;
  const int tid = threadIdx.x;
  const int lane = tid & 63, wave = tid >> 6;
  const int ln31 = lane & 31, lhi = lane >> 5;

  const float* xn = x + (size_t)img * 64 * HW;

  // ---- prologue: stage quarter 0 (c = 0..15) directly ----
  // Item i = (h, cgl, w) over 18*2*34 = 1224; lane-consecutive 16B LDS writes.
  for (int i = tid; i < 1224; i += 512) {
    const int h   = i / 68;
    const int rem = i - h * 68;
    const int cgl = rem / 34;
    const int w   = rem - cgl * 34;
    const int gh  = h0 - 1 + h;
    const int gw  = w0 - 1 + w;
    ushort8 pk;
    if (((unsigned)gh < 224u) && ((unsigned)gw < 224u)) {
      const float* p = xn + (size_t)(cgl * 8) * HW + gh * 224 + gw;
#pragma unroll
      for (int j = 0; j < 8; ++j) pk[j] = f2bf(p[(size_t)j * HW]);
    } else {
#pragma unroll
      for (int j = 0; j < 8; ++j) pk[j] = 0;
    }
    *reinterpret_cast<ushort8*>(&xs[0][i * 8]) = pk;
  }
  __syncthreads();

  // ---- pipelined main loop over 4 c-quarters ----
  const int row0 = wave * 2;  // wave owns rows {row0, row0+1}
  float16_t acc[2][2];
#pragma unroll
  for (int rb = 0; rb < 2; ++rb)
#pragma unroll
    for (int nb = 0; nb < 2; ++nb) acc[rb][nb] = 0.f;

#pragma unroll
  for (int q = 0; q < 4; ++q) {
    // -- 1. issue next-quarter loads into registers (q < 3) --
    float pf[3][8];
    bool  pin[3];
    bool  pvw[3];
    int   pidx[3];
    if (q < 3) {
#pragma unroll
      for (int u = 0; u < 3; ++u) {
        const int i  = tid + u * 512;
        const bool vw = (i < 1224);
        const int ii = vw ? i : 0;
        const int h   = ii / 68;
        const int rem = ii - h * 68;
        const int cgl = rem / 34;
        const int w   = rem - cgl * 34;
        const int gh  = h0 - 1 + h;
        const int gw  = w0 - 1 + w;
        const bool inb = vw && ((unsigned)gh < 224u) && ((unsigned)gw < 224u);
        const int ghc = min(max(gh, 0), 223);
        const int gwc = min(max(gw, 0), 223);
        const float* p = xn + (size_t)(((q + 1) * 2 + cgl) * 8) * HW + ghc * 224 + gwc;
#pragma unroll
        for (int j = 0; j < 8; ++j) pf[u][j] = p[(size_t)j * HW];
        pin[u] = inb; pvw[u] = vw; pidx[u] = ii;
      }
    }

    // -- 2. MFMA quarter q from xs[q&1]: 9 taps x 2 rb x 2 nb = 36 MFMAs/wave --
    const unsigned short* xq = &xs[q & 1][0];
#pragma unroll
    for (int r = 0; r < 3; ++r) {
#pragma unroll
      for (int s = 0; s < 3; ++s) {
        const int tap = r * 3 + s;
        // B-frag: lane n=ln31, k = q*16 + lhi*8 + j. Quarter slice = 18.4KB, L1-hot.
        const short8 b0 = *reinterpret_cast<const short8*>(
            wt + ((tap * 64 + ln31) * 64 + q * 16 + lhi * 8));
        const short8 b1 = *reinterpret_cast<const short8*>(
            wt + ((tap * 64 + 32 + ln31) * 64 + q * 16 + lhi * 8));
#pragma unroll
        for (int rb = 0; rb < 2; ++rb) {
          const int hidx = row0 + rb + r;
          const int widx = ln31 + s;
          // A-frag: lane m=ln31 (w), k = q*16 + lhi*8 + j -> cgl = lhi.
          const short8 a = *reinterpret_cast<const short8*>(
              &xq[((hidx * 2 + lhi) * 34 + widx) * 8]);
          acc[rb][0] = __builtin_amdgcn_mfma_f32_32x32x16_bf16(a, b0, acc[rb][0], 0, 0, 0);
          acc[rb][1] = __builtin_amdgcn_mfma_f32_32x32x16_bf16(a, b1, acc[rb][1], 0, 0, 0);
        }
      }
    }

    // -- 3. convert + write next quarter (loads returned during MFMA) --
    if (q < 3) {
#pragma unroll
      for (int u = 0; u < 3; ++u) {
        if (pvw[u]) {
          ushort8 pk;
#pragma unroll
          for (int j = 0; j < 8; ++j) pk[j] = pin[u] ? f2bf(pf[u][j]) : (unsigned short)0;
          *reinterpret_cast<ushort8*>(&xs[(q + 1) & 1][pidx[u] * 8]) = pk;
        }
      }
    }
    // -- 4. barrier: next quarter visible; buf[q&1] reads all done --
    __syncthreads();
  }

  // ---- epilogue: D lane mapping m=(reg&3)+8*(reg>>2)+4*lhi, n=ln31 ----
  // (r4 pattern: proven 241MB WRITE_SIZE)
#pragma unroll
  for (int rb = 0; rb < 2; ++rb) {
    const int h = h0 + row0 + rb;
#pragma unroll
    for (int nb = 0; nb < 2; ++nb) {
      const int ch = nb * 32 + ln31;
      const float bv = bias[ch];
      float* op = out + (((size_t)img * 64 + ch) * 224 + h) * 224 + w0;
#pragma unroll
      for (int qq = 0; qq < 4; ++qq) {
        const int wloc = 8 * qq + 4 * lhi;
        float4 v;
        v.x = acc[rb][nb][4 * qq + 0] + bv;
        v.y = acc[rb][nb][4 * qq + 1] + bv;
        v.z = acc[rb][nb][4 * qq + 2] + bv;
        v.w = acc[rb][nb][4 * qq + 3] + bv;
        *reinterpret_cast<float4*>(op + wloc) = v;
      }
    }
  }
}

// ---- fallback (round-1 direct fp32) if d_ws is too small for Wt ----
#define TW 32
#define TH 32
#define KB 16
#define PXT 4
__global__ __launch_bounds__(256) void conv3x3_direct(
    const float* __restrict__ x, const float* __restrict__ wgt,
    const float* __restrict__ bias, float* __restrict__ out) {
  __shared__ float xsf[34 * 35];
  const int tx = blockIdx.x % 7, ty = blockIdx.x / 7;
  const int k0 = blockIdx.y * KB, n = blockIdx.z;
  const int w0 = tx * TW, h0 = ty * TH;
  const int tid = threadIdx.x;
  const int tw = tid & 7, th = tid >> 3;
  float acc[KB][PXT];
#pragma unroll
  for (int k = 0; k < KB; ++k)
#pragma unroll
    for (int p = 0; p < PXT; ++p) acc[k][p] = 0.f;
  const float* xn = x + (size_t)n * 64 * HW;
  for (int c = 0; c < 64; ++c) {
    const float* xc = xn + (size_t)c * HW;
    for (int i = tid; i < 34 * 34; i += 256) {
      int row = i / 34, col = i - row * 34;
      int gh = h0 - 1 + row, gw = w0 - 1 + col;
      float v = 0.f;
      if (gh >= 0 && gh < 224 && gw >= 0 && gw < 224) v = xc[gh * 224 + gw];
      xsf[row * 35 + col] = v;
    }
    __syncthreads();
    float in[3][6];
#pragma unroll
    for (int r = 0; r < 3; ++r)
#pragma unroll
      for (int q = 0; q < 6; ++q) in[r][q] = xsf[(th + r) * 35 + tw * PXT + q];
    const float* wc = wgt + ((size_t)k0 * 64 + c) * 9;
#pragma unroll
    for (int k = 0; k < KB; ++k) {
      const float* wk = wc + (size_t)k * 64 * 9;
#pragma unroll
      for (int r = 0; r < 3; ++r)
#pragma unroll
        for (int s = 0; s < 3; ++s) {
          float wv = wk[r * 3 + s];
#pragma unroll
          for (int p = 0; p < PXT; ++p) acc[k][p] += wv * in[r][s + p];
        }
    }
    __syncthreads();
  }
#pragma unroll
  for (int k = 0; k < KB; ++k) {
    float bv = bias[k0 + k];
    float4 v = make_float4(acc[k][0] + bv, acc[k][1] + bv, acc[k][2] + bv, acc[k][3] + bv);
    float* op = out + ((((size_t)n * 64 + (k0 + k)) * 224 + (h0 + th)) * 224 + (w0 + tw * PXT));
    *reinterpret_cast<float4*>(op) = v;
  }
}

extern "C" void kernel_launch(void* const* d_in, const int* in_sizes, int n_in,
                              void* d_out, int out_size, void* d_ws, size_t ws_size,
                              hipStream_t stream) {
  const float* x = (const float*)d_in[0];
  const float* W = (const float*)d_in[1];
  const float* b = (const float*)d_in[2];
  float* out = (float*)d_out;

  if (ws_size >= 9 * 64 * 64 * sizeof(unsigned short)) {
    unsigned short* wt = (unsigned short*)d_ws;
    build_wt<<<144, 256, 0, stream>>>(W, wt);
    conv3x3_mfma<<<1568, 512, 0, stream>>>(x, wt, b, out);  // 7x14x16 tiles, XCD-swizzled
  } else {
    dim3 grid(7 * 7, 64 / KB, 16);
    conv3x3_direct<<<grid, 256, 0, stream>>>(x, W, b, out);
  }
}

// Round 7
// 478.199 us; speedup vs baseline: 1.0187x; 1.0112x over previous
//
#include <hip/hip_runtime.h>
#include <hip/hip_bf16.h>

// bf16 implicit-GEMM 3x3 conv for x:(16,64,224,224) f32, W:(64,64,3,3) f32, b:(64).
// 9 tap-shifted GEMMs (M=pixels, N=64 kout, K=64 c) on v_mfma_f32_32x32x16_bf16.
// Round-7: FULL-WIDTH TILES. Evidence r0-r6: dur ~220-250us invariant vs bytes
// (655->317MB), occupancy (19->38%), batching, pipelining => limited by per-CU
// line-request rate / DRAM fragmentation: 32-wide tiles make every (c,h) read a
// 136B fragment (3 lines, 2 wasted-shared) and every (ch,h) write a 128B
// fragment, all at 200KB channel stride. ~5.4M unique read lines.
// Change: tile = 2 out rows x 224 (FULL width) x 64 kout. No horizontal halo;
// reads become 904B contiguous runs, writes 896B runs; unique read lines -40%.
// Block: 448 thr / 7 waves; wave owns 2 m-tiles (32px) x 64 kout; acc[2][2]=64.
// K split in 2 halves of 32c; LDS [hl(4)][cgl(4)][w(226)][c8(8)] = 57856B,
// single-buffered -> 2 blocks/CU (115.7KB) with __launch_bounds__(448,4).
// Grid 1792 = 112 h-tiles x 16 img, XCD-chunked: 224 tiles = exactly 2 images
// per XCD -> vertical halo rows L2-shared.
// Kept: wt[tap][kout][c] bf16 in d_ws, r4 float4 epilogue, conflict-free
// lane-consecutive 16B LDS writes.

typedef __attribute__((ext_vector_type(8)))  short   short8;
typedef __attribute__((ext_vector_type(8)))  unsigned short ushort8;
typedef __attribute__((ext_vector_type(16))) float   float16_t;

#define HW (224 * 224)

__device__ __forceinline__ unsigned short f2bf(float f) {
  __hip_bfloat16 h = __float2bfloat16(f);  // RNE
  return *reinterpret_cast<unsigned short*>(&h);
}

// ---- pre-kernel: Wt[tap][kout][c] bf16 <- W[kout][c][tap] fp32 ----
__global__ void build_wt(const float* __restrict__ W, unsigned short* __restrict__ wt) {
  int i = blockIdx.x * 256 + threadIdx.x;  // 0 .. 36863
  if (i < 9 * 64 * 64) {
    int tap = i >> 12;          // /4096
    int rem = i & 4095;
    int nn  = rem >> 6;
    int c   = rem & 63;
    wt[i] = f2bf(W[(nn * 64 + c) * 9 + tap]);
  }
}

// ---- main kernel ----
// Grid: 1792 1-D blocks = 112 h-tiles x 16 images, XCD-swizzled.
__global__ __launch_bounds__(448, 4) void conv3x3_mfma(
    const float* __restrict__ x, const unsigned short* __restrict__ wt,
    const float* __restrict__ bias, float* __restrict__ out) {
  // [hl(4)][cgl(4)][w(226)][c8(8)] bf16 = 28928 shorts = 57856 B.
  __shared__ __align__(16) unsigned short xs[4 * 4 * 226 * 8];

  // XCD-chunked swizzle: hw assigns XCD = bid % 8. Contiguous 224-tile chunk
  // (= 2 whole images) per XCD so vertical-halo rows are L2-shared. 1792%8==0.
  const int bid = blockIdx.x;
  const int t   = (bid & 7) * 224 + (bid >> 3);
  const int ht  = t % 112;
  const int img = t / 112;
  const int h0  = ht * 2;          // output rows h0, h0+1

  const int tid = threadIdx.x;
  const int lane = tid & 63, wave = tid >> 6;   // wave 0..6
  const int ln31 = lane & 31, lhi = lane >> 5;

  const float* xn = x + (size_t)img * 64 * HW;

  float16_t acc[2][2];
#pragma unroll
  for (int mt2 = 0; mt2 < 2; ++mt2)
#pragma unroll
    for (int nb = 0; nb < 2; ++nb) acc[mt2][nb] = 0.f;

  // ---- K loop: 2 halves of 32 channels ----
  for (int half = 0; half < 2; ++half) {
    // -- stage 4 input rows x 32 c x 226 w (full width + 1-col pad each side) --
    // Item i = (hl, cgl, w), w fastest: coalesced 4B global reads per channel
    // (64 consecutive w per wave-instruction = 256B), lane-consecutive 16B LDS
    // writes (conflict-free, measured 0 across r0-r6).
    for (int i = tid; i < 4 * 4 * 226; i += 448) {
      const int hcg = i / 226;         // hl*4 + cgl
      const int w   = i - hcg * 226;
      const int hl  = hcg >> 2;
      const int cgl = hcg & 3;
      const int gh  = h0 - 1 + hl;
      const int gw  = w - 1;
      ushort8 pk;
      if (((unsigned)gh < 224u) && ((unsigned)gw < 224u)) {
        const float* p = xn + (size_t)(half * 32 + cgl * 8) * HW + gh * 224 + gw;
#pragma unroll
        for (int j = 0; j < 8; ++j) pk[j] = f2bf(p[(size_t)j * HW]);
      } else {
#pragma unroll
        for (int j = 0; j < 8; ++j) pk[j] = 0;
      }
      *reinterpret_cast<ushort8*>(&xs[i * 8]) = pk;
    }
    __syncthreads();

    // -- MFMA: 2 ksteps x 9 taps x 2 m-tiles x 2 nb = 72 MFMAs/wave/half --
#pragma unroll
    for (int ks = 0; ks < 2; ++ks) {
#pragma unroll
      for (int r = 0; r < 3; ++r) {
#pragma unroll
        for (int s = 0; s < 3; ++s) {
          const int tap = r * 3 + s;
          // B-frag: lane n=ln31 (kout), k = half*32 + ks*16 + lhi*8 + j.
          const short8 b0 = *reinterpret_cast<const short8*>(
              wt + ((tap * 64 + ln31) * 64 + half * 32 + ks * 16 + lhi * 8));
          const short8 b1 = *reinterpret_cast<const short8*>(
              wt + ((tap * 64 + 32 + ln31) * 64 + half * 32 + ks * 16 + lhi * 8));
          const int cgl = ks * 2 + lhi;
#pragma unroll
          for (int mt2 = 0; mt2 < 2; ++mt2) {
            const int mt = wave * 2 + mt2;      // m-tile 0..13
            const int hh = mt / 7;              // 0..1 output row within tile
            const int w0 = (mt - hh * 7) * 32;  // 0,32,..,192
            // A-frag: lane m=ln31 (w-pixel), k = cgl*8 + j within half.
            const short8 a = *reinterpret_cast<const short8*>(
                &xs[((((hh + r) * 4) + cgl) * 226 + (w0 + ln31 + s)) * 8]);
            acc[mt2][0] = __builtin_amdgcn_mfma_f32_32x32x16_bf16(a, b0, acc[mt2][0], 0, 0, 0);
            acc[mt2][1] = __builtin_amdgcn_mfma_f32_32x32x16_bf16(a, b1, acc[mt2][1], 0, 0, 0);
          }
        }
      }
    }
    if (half == 0) __syncthreads();  // all reads done before restaging
  }

  // ---- epilogue: D col(ln31)=kout, row m=(reg&3)+8*(reg>>2)+4*lhi = w-pixel ----
  // (r4 float4 pattern; block collectively covers full 896B rows per (ch,h))
#pragma unroll
  for (int mt2 = 0; mt2 < 2; ++mt2) {
    const int mt = wave * 2 + mt2;
    const int hh = mt / 7;
    const int w0 = (mt - hh * 7) * 32;
    const int h  = h0 + hh;
#pragma unroll
    for (int nb = 0; nb < 2; ++nb) {
      const int ch = nb * 32 + ln31;
      const float bv = bias[ch];
      float* op = out + (((size_t)img * 64 + ch) * 224 + h) * 224 + w0;
#pragma unroll
      for (int q = 0; q < 4; ++q) {
        const int wloc = 8 * q + 4 * lhi;
        float4 v;
        v.x = acc[mt2][nb][4 * q + 0] + bv;
        v.y = acc[mt2][nb][4 * q + 1] + bv;
        v.z = acc[mt2][nb][4 * q + 2] + bv;
        v.w = acc[mt2][nb][4 * q + 3] + bv;
        *reinterpret_cast<float4*>(op + wloc) = v;
      }
    }
  }
}

// ---- fallback (round-1 direct fp32) if d_ws is too small for Wt ----
#define TW 32
#define TH 32
#define KB 16
#define PXT 4
__global__ __launch_bounds__(256) void conv3x3_direct(
    const float* __restrict__ x, const float* __restrict__ wgt,
    const float* __restrict__ bias, float* __restrict__ out) {
  __shared__ float xsf[34 * 35];
  const int tx = blockIdx.x % 7, ty = blockIdx.x / 7;
  const int k0 = blockIdx.y * KB, n = blockIdx.z;
  const int w0 = tx * TW, h0 = ty * TH;
  const int tid = threadIdx.x;
  const int tw = tid & 7, th = tid >> 3;
  float acc[KB][PXT];
#pragma unroll
  for (int k = 0; k < KB; ++k)
#pragma unroll
    for (int p = 0; p < PXT; ++p) acc[k][p] = 0.f;
  const float* xn = x + (size_t)n * 64 * HW;
  for (int c = 0; c < 64; ++c) {
    const float* xc = xn + (size_t)c * HW;
    for (int i = tid; i < 34 * 34; i += 256) {
      int row = i / 34, col = i - row * 34;
      int gh = h0 - 1 + row, gw = w0 - 1 + col;
      float v = 0.f;
      if (gh >= 0 && gh < 224 && gw >= 0 && gw < 224) v = xc[gh * 224 + gw];
      xsf[row * 35 + col] = v;
    }
    __syncthreads();
    float in[3][6];
#pragma unroll
    for (int r = 0; r < 3; ++r)
#pragma unroll
      for (int q = 0; q < 6; ++q) in[r][q] = xsf[(th + r) * 35 + tw * PXT + q];
    const float* wc = wgt + ((size_t)k0 * 64 + c) * 9;
#pragma unroll
    for (int k = 0; k < KB; ++k) {
      const float* wk = wc + (size_t)k * 64 * 9;
#pragma unroll
      for (int r = 0; r < 3; ++r)
#pragma unroll
        for (int s = 0; s < 3; ++s) {
          float wv = wk[r * 3 + s];
#pragma unroll
          for (int p = 0; p < PXT; ++p) acc[k][p] += wv * in[r][s + p];
        }
    }
    __syncthreads();
  }
#pragma unroll
  for (int k = 0; k < KB; ++k) {
    float bv = bias[k0 + k];
    float4 v = make_float4(acc[k][0] + bv, acc[k][1] + bv, acc[k][2] + bv, acc[k][3] + bv);
    float* op = out + ((((size_t)n * 64 + (k0 + k)) * 224 + (h0 + th)) * 224 + (w0 + tw * PXT));
    *reinterpret_cast<float4*>(op) = v;
  }
}

extern "C" void kernel_launch(void* const* d_in, const int* in_sizes, int n_in,
                              void* d_out, int out_size, void* d_ws, size_t ws_size,
                              hipStream_t stream) {
  const float* x = (const float*)d_in[0];
  const float* W = (const float*)d_in[1];
  const float* b = (const float*)d_in[2];
  float* out = (float*)d_out;

  if (ws_size >= 9 * 64 * 64 * sizeof(unsigned short)) {
    unsigned short* wt = (unsigned short*)d_ws;
    build_wt<<<144, 256, 0, stream>>>(W, wt);
    conv3x3_mfma<<<1792, 448, 0, stream>>>(x, wt, b, out);  // 112 h-tiles x 16 img
  } else {
    dim3 grid(7 * 7, 64 / KB, 16);
    conv3x3_direct<<<grid, 256, 0, stream>>>(x, W, b, out);
  }
}